// Round 1
// baseline (5623.863 us; speedup 1.0000x reference)
//
#include <hip/hip_runtime.h>
#include <math.h>

// Problem constants
#define BATCH 65536
#define XD 362
#define ZD 100

// ws layout (bytes):
//   [0,256)                     : counts[3] (int), zeroed each launch
//   [256, 256+786432)           : idxlist[3][65536] (int)
//   [786688, +26214400)         : z [B][100] float
//   [27001088, +3784704)        : repacked transposed weights (float)
#define WS_IDX_OFF    256
#define WS_Z_OFF      786688
#define WS_WT_OFF     27001088

// Transposed-weight float offsets inside the weight region
#define OFF_W1T   0         // [256][364]
#define OFF_W2T   93184     // [256][256]
#define OFF_W3T   158720    // [128][200]
#define OFF_EW1T  184320    // 3 x [192][100]
#define OFF_EW2T  241920    // 3 x [256][152]
#define OFF_EW3T  358656    // 3 x [320][252]
#define OFF_EW4T  600576    // 3 x [384][300]

__device__ __forceinline__ float dot4(float acc, float4 a, float4 w) {
    acc = fmaf(a.x, w.x, acc);
    acc = fmaf(a.y, w.y, acc);
    acc = fmaf(a.z, w.z, acc);
    acc = fmaf(a.w, w.w, acc);
    return acc;
}

// Generic fused layer: out[32][LDO] = act(in[32][K4] @ Wt^T + b)
// Wt is transposed+padded [N64][K4] (zeros beyond K,N). in LDS ld == K4.
// Each thread: rows (ty, ty+16), 4 cols starting at ct*64 + tx*4.
// ACT: 0 = relu
template <int ACT, int K4, int N>
__device__ __forceinline__ void mlp_layer(const float* __restrict__ Wt,
                                          const float* __restrict__ bias,
                                          const float* __restrict__ inL,
                                          float* __restrict__ outL,
                                          int tx, int ty) {
    constexpr int LDO = (N + 3) & ~3;
    constexpr int NT = (N + 63) / 64;
    const float* a0 = inL + ty * K4;
    const float* a1 = inL + (ty + 16) * K4;
    for (int ct = 0; ct < NT; ++ct) {
        const int c = ct * 64 + tx * 4;
        float acc0[4], acc1[4];
#pragma unroll
        for (int j = 0; j < 4; ++j) {
            float bv = (c + j < N) ? bias[c + j] : 0.0f;
            acc0[j] = bv; acc1[j] = bv;
        }
        const float* w = Wt + (size_t)c * K4;
#pragma unroll 2
        for (int k = 0; k < K4; k += 4) {
            float4 va0 = *(const float4*)(a0 + k);
            float4 va1 = *(const float4*)(a1 + k);
            float4 w0 = *(const float4*)(w + k);
            float4 w1 = *(const float4*)(w + K4 + k);
            float4 w2 = *(const float4*)(w + 2 * K4 + k);
            float4 w3 = *(const float4*)(w + 3 * K4 + k);
            acc0[0] = dot4(acc0[0], va0, w0);
            acc0[1] = dot4(acc0[1], va0, w1);
            acc0[2] = dot4(acc0[2], va0, w2);
            acc0[3] = dot4(acc0[3], va0, w3);
            acc1[0] = dot4(acc1[0], va1, w0);
            acc1[1] = dot4(acc1[1], va1, w1);
            acc1[2] = dot4(acc1[2], va1, w2);
            acc1[3] = dot4(acc1[3], va1, w3);
        }
#pragma unroll
        for (int j = 0; j < 4; ++j) {
            int cj = c + j;
            if (cj < LDO) {
                float v0 = acc0[j], v1 = acc1[j];
                if (ACT == 0) { v0 = fmaxf(v0, 0.0f); v1 = fmaxf(v1, 0.0f); }
                outL[ty * LDO + cj]        = (cj < N) ? v0 : 0.0f;
                outL[(ty + 16) * LDO + cj] = (cj < N) ? v1 : 0.0f;
            }
        }
    }
}

// ---------------- repack: W[K][N] (row-major) -> Wt[N64][K4], zero-padded ---
__global__ __launch_bounds__(256) void repack_kernel(
    const float* __restrict__ W1, const float* __restrict__ W2,
    const float* __restrict__ W3, const float* __restrict__ eW1,
    const float* __restrict__ eW2, const float* __restrict__ eW3,
    const float* __restrict__ eW4, float* __restrict__ dst) {
    int m = blockIdx.y;
    const float* src; int K, N, K4, N64; size_t doff;
    if (m == 0)      { src = W1; K = 362; N = 256; K4 = 364; N64 = 256; doff = OFF_W1T; }
    else if (m == 1) { src = W2; K = 256; N = 200; K4 = 256; N64 = 256; doff = OFF_W2T; }
    else if (m == 2) { src = W3; K = 200; N = 100; K4 = 200; N64 = 128; doff = OFF_W3T; }
    else if (m <= 5) { int e = m - 3;  src = eW1 + e * 15000;  K = 100; N = 150; K4 = 100; N64 = 192; doff = OFF_EW1T + (size_t)e * 19200; }
    else if (m <= 8) { int e = m - 6;  src = eW2 + e * 37500;  K = 150; N = 250; K4 = 152; N64 = 256; doff = OFF_EW2T + (size_t)e * 38912; }
    else if (m <= 11){ int e = m - 9;  src = eW3 + e * 75000;  K = 250; N = 300; K4 = 252; N64 = 320; doff = OFF_EW3T + (size_t)e * 80640; }
    else             { int e = m - 12; src = eW4 + e * 108600; K = 300; N = 362; K4 = 300; N64 = 384; doff = OFF_EW4T + (size_t)e * 115200; }
    int total = K4 * N64;
    for (int i = blockIdx.x * 256 + threadIdx.x; i < total; i += gridDim.x * 256) {
        int n = i / K4;
        int k = i - n * K4;
        dst[doff + i] = (k < K && n < N) ? src[(size_t)k * N + n] : 0.0f;
    }
}

// ---------------- bucket rows by expert -------------------------------------
__global__ __launch_bounds__(256) void bucket_kernel(const int* __restrict__ a,
                                                     int* __restrict__ counts,
                                                     int* __restrict__ idxlist) {
    int b = blockIdx.x * 256 + threadIdx.x;
    if (b >= BATCH) return;
    int e = a[b];
    int pos = atomicAdd(&counts[e], 1);
    idxlist[e * BATCH + pos] = b;
}

// ---------------- fused encoder: x -> z -------------------------------------
__global__ __launch_bounds__(256) void encoder_kernel(
    const float* __restrict__ x,
    const float* __restrict__ W1t, const float* __restrict__ b1,
    const float* __restrict__ W2t, const float* __restrict__ b2,
    const float* __restrict__ W3t, const float* __restrict__ b3,
    float* __restrict__ z) {
    __shared__ float bufA[32 * 364];
    __shared__ float bufB[32 * 256];
    int tid = threadIdx.x;
    int tx = tid & 15, ty = tid >> 4;
    int rowbase = blockIdx.x * 32;
    // stage x tile (zero-pad k=362..363)
    for (int i = tid; i < 32 * 364; i += 256) {
        int r = i / 364;
        int k = i - r * 364;
        bufA[i] = (k < 362) ? x[(size_t)(rowbase + r) * 362 + k] : 0.0f;
    }
    __syncthreads();
    mlp_layer<0, 364, 256>(W1t, b1, bufA, bufB, tx, ty);
    __syncthreads();
    mlp_layer<0, 256, 200>(W2t, b2, bufB, bufA, tx, ty);
    __syncthreads();
    // L3: K4=200, N=100, sigmoid, store to global z
    {
        const float* a0 = bufA + ty * 200;
        const float* a1 = bufA + (ty + 16) * 200;
        for (int ct = 0; ct < 2; ++ct) {
            int c = ct * 64 + tx * 4;
            if (c < 100) {
                float acc0[4], acc1[4];
#pragma unroll
                for (int j = 0; j < 4; ++j) { float bv = b3[c + j]; acc0[j] = bv; acc1[j] = bv; }
                const float* w = W3t + (size_t)c * 200;
#pragma unroll 2
                for (int k = 0; k < 200; k += 4) {
                    float4 va0 = *(const float4*)(a0 + k);
                    float4 va1 = *(const float4*)(a1 + k);
                    float4 w0 = *(const float4*)(w + k);
                    float4 w1 = *(const float4*)(w + 200 + k);
                    float4 w2 = *(const float4*)(w + 400 + k);
                    float4 w3 = *(const float4*)(w + 600 + k);
                    acc0[0] = dot4(acc0[0], va0, w0);
                    acc0[1] = dot4(acc0[1], va0, w1);
                    acc0[2] = dot4(acc0[2], va0, w2);
                    acc0[3] = dot4(acc0[3], va0, w3);
                    acc1[0] = dot4(acc1[0], va1, w0);
                    acc1[1] = dot4(acc1[1], va1, w1);
                    acc1[2] = dot4(acc1[2], va1, w2);
                    acc1[3] = dot4(acc1[3], va1, w3);
                }
                float4 z0, z1;
                z0.x = 1.0f / (1.0f + expf(-acc0[0]));
                z0.y = 1.0f / (1.0f + expf(-acc0[1]));
                z0.z = 1.0f / (1.0f + expf(-acc0[2]));
                z0.w = 1.0f / (1.0f + expf(-acc0[3]));
                z1.x = 1.0f / (1.0f + expf(-acc1[0]));
                z1.y = 1.0f / (1.0f + expf(-acc1[1]));
                z1.z = 1.0f / (1.0f + expf(-acc1[2]));
                z1.w = 1.0f / (1.0f + expf(-acc1[3]));
                *(float4*)(&z[(size_t)(rowbase + ty) * 100 + c]) = z0;
                *(float4*)(&z[(size_t)(rowbase + ty + 16) * 100 + c]) = z1;
            }
        }
    }
}

// ---------------- fused expert chain + loss ---------------------------------
__global__ __launch_bounds__(256) void expert_kernel(
    const float* __restrict__ z, const int* __restrict__ counts,
    const int* __restrict__ idxlist, const float* __restrict__ Wts,
    const float* __restrict__ eb1, const float* __restrict__ eb2,
    const float* __restrict__ eb3, const float* __restrict__ eb4,
    const float* __restrict__ x, const float* __restrict__ xn,
    float* __restrict__ out) {
    int e = blockIdx.y;
    int cnt = counts[e];
    int start = blockIdx.x * 32;
    if (start >= cnt) return;
    int nrows = min(32, cnt - start);

    __shared__ float bufA[32 * 252];
    __shared__ float bufB[32 * 300];
    __shared__ int s_idx[32];
    __shared__ float s_part[4];

    int tid = threadIdx.x;
    int tx = tid & 15, ty = tid >> 4;

    if (tid < 32)
        s_idx[tid] = (tid < nrows) ? idxlist[e * BATCH + start + tid] : -1;
    __syncthreads();
    // gather z rows (ld = 100)
    for (int i = tid; i < 32 * 100; i += 256) {
        int r = i / 100;
        int k = i - r * 100;
        int b = s_idx[r];
        bufA[i] = (b >= 0) ? z[(size_t)b * 100 + k] : 0.0f;
    }
    __syncthreads();

    const float* W1t = Wts + OFF_EW1T + (size_t)e * 19200;
    const float* W2t = Wts + OFF_EW2T + (size_t)e * 38912;
    const float* W3t = Wts + OFF_EW3T + (size_t)e * 80640;
    const float* W4t = Wts + OFF_EW4T + (size_t)e * 115200;

    mlp_layer<0, 100, 150>(W1t, eb1 + e * 150, bufA, bufB, tx, ty);
    __syncthreads();
    mlp_layer<0, 152, 250>(W2t, eb2 + e * 250, bufB, bufA, tx, ty);
    __syncthreads();
    mlp_layer<0, 252, 300>(W3t, eb3 + e * 300, bufA, bufB, tx, ty);
    __syncthreads();

    // L4 (300 -> 362, no act) fused with loss
    const float WC0 = 1.0f / 65536.0f;
    const float WCR = 1.0f / (361.0f * 65536.0f);
    const float* bias4 = eb4 + (size_t)e * 362;
    const float* a0 = bufB + ty * 300;
    const float* a1 = bufB + (ty + 16) * 300;
    int b0 = s_idx[ty];
    int b1i = s_idx[ty + 16];
    float lacc = 0.0f;
    for (int ct = 0; ct < 6; ++ct) {
        int c = ct * 64 + tx * 4;
        float acc0[4], acc1[4];
#pragma unroll
        for (int j = 0; j < 4; ++j) {
            float bv = (c + j < 362) ? bias4[c + j] : 0.0f;
            acc0[j] = bv; acc1[j] = bv;
        }
        const float* w = W4t + (size_t)c * 300;
#pragma unroll 2
        for (int k = 0; k < 300; k += 4) {
            float4 va0 = *(const float4*)(a0 + k);
            float4 va1 = *(const float4*)(a1 + k);
            float4 w0 = *(const float4*)(w + k);
            float4 w1 = *(const float4*)(w + 300 + k);
            float4 w2 = *(const float4*)(w + 600 + k);
            float4 w3 = *(const float4*)(w + 900 + k);
            acc0[0] = dot4(acc0[0], va0, w0);
            acc0[1] = dot4(acc0[1], va0, w1);
            acc0[2] = dot4(acc0[2], va0, w2);
            acc0[3] = dot4(acc0[3], va0, w3);
            acc1[0] = dot4(acc1[0], va1, w0);
            acc1[1] = dot4(acc1[1], va1, w1);
            acc1[2] = dot4(acc1[2], va1, w2);
            acc1[3] = dot4(acc1[3], va1, w3);
        }
        if (b0 >= 0) {
            const float* xb = x + (size_t)b0 * 362;
            const float* nb = xn + (size_t)b0 * 362;
#pragma unroll
            for (int j = 0; j < 4; ++j) {
                int cj = c + j;
                if (cj < 362) {
                    float err = acc0[j] - (nb[cj] - xb[cj]);
                    float wgt = (cj == 0) ? WC0 : WCR;
                    lacc += wgt * err * err;
                }
            }
        }
        if (b1i >= 0) {
            const float* xb = x + (size_t)b1i * 362;
            const float* nb = xn + (size_t)b1i * 362;
#pragma unroll
            for (int j = 0; j < 4; ++j) {
                int cj = c + j;
                if (cj < 362) {
                    float err = acc1[j] - (nb[cj] - xb[cj]);
                    float wgt = (cj == 0) ? WC0 : WCR;
                    lacc += wgt * err * err;
                }
            }
        }
    }
    // block reduction -> atomicAdd
    int lane = tid & 63;
    int wid = tid >> 6;
    for (int off = 32; off; off >>= 1)
        lacc += __shfl_down(lacc, off, 64);
    if (lane == 0) s_part[wid] = lacc;
    __syncthreads();
    if (tid == 0) {
        float t = s_part[0] + s_part[1] + s_part[2] + s_part[3];
        atomicAdd(out, t);
    }
}

extern "C" void kernel_launch(void* const* d_in, const int* in_sizes, int n_in,
                              void* d_out, int out_size, void* d_ws, size_t ws_size,
                              hipStream_t stream) {
    const float* x   = (const float*)d_in[0];
    const float* xn  = (const float*)d_in[1];
    const int*   a   = (const int*)d_in[2];
    const float* W1  = (const float*)d_in[3];
    const float* b1  = (const float*)d_in[4];
    const float* W2  = (const float*)d_in[5];
    const float* b2  = (const float*)d_in[6];
    const float* W3  = (const float*)d_in[7];
    const float* b3  = (const float*)d_in[8];
    const float* eW1 = (const float*)d_in[9];
    const float* eb1 = (const float*)d_in[10];
    const float* eW2 = (const float*)d_in[11];
    const float* eb2 = (const float*)d_in[12];
    const float* eW3 = (const float*)d_in[13];
    const float* eb3 = (const float*)d_in[14];
    const float* eW4 = (const float*)d_in[15];
    const float* eb4 = (const float*)d_in[16];

    char* ws = (char*)d_ws;
    int* counts  = (int*)ws;
    int* idxlist = (int*)(ws + WS_IDX_OFF);
    float* z     = (float*)(ws + WS_Z_OFF);
    float* Wts   = (float*)(ws + WS_WT_OFF);

    hipMemsetAsync(counts, 0, 256, stream);
    hipMemsetAsync(d_out, 0, sizeof(float), stream);

    repack_kernel<<<dim3(128, 15), 256, 0, stream>>>(W1, W2, W3, eW1, eW2, eW3, eW4, Wts);
    bucket_kernel<<<BATCH / 256, 256, 0, stream>>>(a, counts, idxlist);
    encoder_kernel<<<BATCH / 32, 256, 0, stream>>>(
        x, Wts + OFF_W1T, b1, Wts + OFF_W2T, b2, Wts + OFF_W3T, b3, z);
    expert_kernel<<<dim3(BATCH / 32, 3), 256, 0, stream>>>(
        z, counts, idxlist, Wts, eb1, eb2, eb3, eb4, x, xn, (float*)d_out);
}

// Round 2
// 3005.390 us; speedup vs baseline: 1.8713x; 1.8713x over previous
//
#include <hip/hip_runtime.h>
#include <math.h>

// Problem constants
#define BATCH 65536
#define XD 362
#define ZD 100

// ws layout (bytes):
//   [0,256)                     : counts[3] (int), zeroed each launch
//   [256, 256+786432)           : idxlist[3][65536] (int)
//   [786688, +26214400)         : z [B][100] float
//   [27001088, +3788800)        : repacked weights (float), W[K4][N64] zero-padded
#define WS_IDX_OFF    256
#define WS_Z_OFF      786688
#define WS_WT_OFF     27001088

// Padded-weight float offsets inside the weight region. Layout: Wp[K4][N64],
// row-major, zero-padded beyond (K,N). Coalesced: lane tx reads Wp[k][c..c+3].
#define OFF_W1P   0         // [364][256]
#define OFF_W2P   93184     // [260][256]  (K4=260 to break %32==0 LDS stride)
#define OFF_W3P   159744    // [200][128]
#define OFF_EW1P  185344    // 3 x [100][192], stride 19200
#define OFF_EW2P  242944    // 3 x [152][256], stride 38912
#define OFF_EW3P  359680    // 3 x [252][320], stride 80640
#define OFF_EW4P  601600    // 3 x [300][384], stride 115200
// end: 947200 floats = 3788800 bytes

__device__ __forceinline__ void fma4(float acc[4], float a, float4 w) {
    acc[0] = fmaf(a, w.x, acc[0]);
    acc[1] = fmaf(a, w.y, acc[1]);
    acc[2] = fmaf(a, w.z, acc[2]);
    acc[3] = fmaf(a, w.w, acc[3]);
}

// Fused layer: out[32][LDO] = act(in[32][K4] @ Wp + b)
// Wp is [K4][N64] zero-padded. Each thread: rows (ty, ty+16), cols c..c+3,
// c = ct*64 + tx*4  -> weight loads coalesced across tx (256B/wave/row).
// ACT: 0 = relu
template <int ACT, int K4, int N, int N64, int LDO>
__device__ __forceinline__ void mlp_layer(const float* __restrict__ Wp,
                                          const float* __restrict__ bias,
                                          const float* __restrict__ inL,
                                          float* __restrict__ outL,
                                          int tx, int ty) {
    constexpr int NT = N64 / 64;
    const float* a0 = inL + ty * K4;
    const float* a1 = inL + (ty + 16) * K4;
    for (int ct = 0; ct < NT; ++ct) {
        const int c = ct * 64 + tx * 4;
        float acc0[4] = {0.f, 0.f, 0.f, 0.f};
        float acc1[4] = {0.f, 0.f, 0.f, 0.f};
        const float* w = Wp + c;
#pragma unroll 2
        for (int k = 0; k < K4; k += 4) {
            float4 va0 = *(const float4*)(a0 + k);
            float4 va1 = *(const float4*)(a1 + k);
            float4 w0 = *(const float4*)(w + (size_t)(k + 0) * N64);
            float4 w1 = *(const float4*)(w + (size_t)(k + 1) * N64);
            float4 w2 = *(const float4*)(w + (size_t)(k + 2) * N64);
            float4 w3 = *(const float4*)(w + (size_t)(k + 3) * N64);
            fma4(acc0, va0.x, w0); fma4(acc0, va0.y, w1);
            fma4(acc0, va0.z, w2); fma4(acc0, va0.w, w3);
            fma4(acc1, va1.x, w0); fma4(acc1, va1.y, w1);
            fma4(acc1, va1.z, w2); fma4(acc1, va1.w, w3);
        }
#pragma unroll
        for (int j = 0; j < 4; ++j) {
            int cj = c + j;
            if (cj < LDO) {
                float bv = (cj < N) ? bias[cj] : 0.f;
                float v0 = acc0[j] + bv, v1 = acc1[j] + bv;
                if (ACT == 0) { v0 = fmaxf(v0, 0.f); v1 = fmaxf(v1, 0.f); }
                outL[ty * LDO + cj]        = (cj < N) ? v0 : 0.f;
                outL[(ty + 16) * LDO + cj] = (cj < N) ? v1 : 0.f;
            }
        }
    }
}

// ---------------- repack: W[K][N] -> Wp[K4][N64], zero-padded ---------------
__global__ __launch_bounds__(256) void repack_kernel(
    const float* __restrict__ W1, const float* __restrict__ W2,
    const float* __restrict__ W3, const float* __restrict__ eW1,
    const float* __restrict__ eW2, const float* __restrict__ eW3,
    const float* __restrict__ eW4, float* __restrict__ dst) {
    int m = blockIdx.y;
    const float* src; int K, N, K4, N64; size_t doff;
    if (m == 0)      { src = W1; K = 362; N = 256; K4 = 364; N64 = 256; doff = OFF_W1P; }
    else if (m == 1) { src = W2; K = 256; N = 200; K4 = 260; N64 = 256; doff = OFF_W2P; }
    else if (m == 2) { src = W3; K = 200; N = 100; K4 = 200; N64 = 128; doff = OFF_W3P; }
    else if (m <= 5) { int e = m - 3;  src = eW1 + e * 15000;  K = 100; N = 150; K4 = 100; N64 = 192; doff = OFF_EW1P + (size_t)e * 19200; }
    else if (m <= 8) { int e = m - 6;  src = eW2 + e * 37500;  K = 150; N = 250; K4 = 152; N64 = 256; doff = OFF_EW2P + (size_t)e * 38912; }
    else if (m <= 11){ int e = m - 9;  src = eW3 + e * 75000;  K = 250; N = 300; K4 = 252; N64 = 320; doff = OFF_EW3P + (size_t)e * 80640; }
    else             { int e = m - 12; src = eW4 + e * 108600; K = 300; N = 362; K4 = 300; N64 = 384; doff = OFF_EW4P + (size_t)e * 115200; }
    int total = K4 * N64;
    for (int i = blockIdx.x * 256 + threadIdx.x; i < total; i += gridDim.x * 256) {
        int k = i / N64;
        int n = i - k * N64;
        dst[doff + i] = (k < K && n < N) ? src[(size_t)k * N + n] : 0.0f;
    }
}

// ---------------- bucket rows by expert -------------------------------------
__global__ __launch_bounds__(256) void bucket_kernel(const int* __restrict__ a,
                                                     int* __restrict__ counts,
                                                     int* __restrict__ idxlist) {
    int b = blockIdx.x * 256 + threadIdx.x;
    if (b >= BATCH) return;
    int e = a[b];
    int pos = atomicAdd(&counts[e], 1);
    idxlist[e * BATCH + pos] = b;
}

// ---------------- fused encoder: x -> z -------------------------------------
__global__ __launch_bounds__(256) void encoder_kernel(
    const float* __restrict__ x, const float* __restrict__ Wts,
    const float* __restrict__ b1, const float* __restrict__ b2,
    const float* __restrict__ b3, float* __restrict__ z) {
    __shared__ float bufA[32 * 364];   // x tile (ld 364), then L2 out (ld 200)
    __shared__ float bufB[32 * 260];   // L1 out (ld 260)
    int tid = threadIdx.x;
    int tx = tid & 15, ty = tid >> 4;
    int rowbase = blockIdx.x * 32;
    // zero-fill bufB pad cols 256..259 (mlp_layer only writes cj<256 for N=256)
    if (tid < 128) { int r = tid >> 2, cc = 256 + (tid & 3); bufB[r * 260 + cc] = 0.f; }
    // stage x tile (zero-pad k=362..363)
    for (int i = tid; i < 32 * 364; i += 256) {
        int r = i / 364;
        int k = i - r * 364;
        bufA[i] = (k < 362) ? x[(size_t)(rowbase + r) * 362 + k] : 0.0f;
    }
    __syncthreads();
    mlp_layer<0, 364, 256, 256, 260>(Wts + OFF_W1P, b1, bufA, bufB, tx, ty);
    __syncthreads();
    mlp_layer<0, 260, 200, 256, 200>(Wts + OFF_W2P, b2, bufB, bufA, tx, ty);
    __syncthreads();
    // L3: [200]->[100], sigmoid, store to global z (ld 100)
    {
        const float* W3p = Wts + OFF_W3P;
        const float* a0 = bufA + ty * 200;
        const float* a1 = bufA + (ty + 16) * 200;
#pragma unroll
        for (int ct = 0; ct < 2; ++ct) {
            int c = ct * 64 + tx * 4;
            if (c < 100) {
                float acc0[4] = {0.f, 0.f, 0.f, 0.f};
                float acc1[4] = {0.f, 0.f, 0.f, 0.f};
                const float* w = W3p + c;
#pragma unroll 2
                for (int k = 0; k < 200; k += 4) {
                    float4 va0 = *(const float4*)(a0 + k);
                    float4 va1 = *(const float4*)(a1 + k);
                    float4 w0 = *(const float4*)(w + (size_t)(k + 0) * 128);
                    float4 w1 = *(const float4*)(w + (size_t)(k + 1) * 128);
                    float4 w2 = *(const float4*)(w + (size_t)(k + 2) * 128);
                    float4 w3 = *(const float4*)(w + (size_t)(k + 3) * 128);
                    fma4(acc0, va0.x, w0); fma4(acc0, va0.y, w1);
                    fma4(acc0, va0.z, w2); fma4(acc0, va0.w, w3);
                    fma4(acc1, va1.x, w0); fma4(acc1, va1.y, w1);
                    fma4(acc1, va1.z, w2); fma4(acc1, va1.w, w3);
                }
                float4 z0, z1;
                z0.x = 1.0f / (1.0f + expf(-(acc0[0] + b3[c + 0])));
                z0.y = 1.0f / (1.0f + expf(-(acc0[1] + b3[c + 1])));
                z0.z = 1.0f / (1.0f + expf(-(acc0[2] + b3[c + 2])));
                z0.w = 1.0f / (1.0f + expf(-(acc0[3] + b3[c + 3])));
                z1.x = 1.0f / (1.0f + expf(-(acc1[0] + b3[c + 0])));
                z1.y = 1.0f / (1.0f + expf(-(acc1[1] + b3[c + 1])));
                z1.z = 1.0f / (1.0f + expf(-(acc1[2] + b3[c + 2])));
                z1.w = 1.0f / (1.0f + expf(-(acc1[3] + b3[c + 3])));
                *(float4*)(&z[(size_t)(rowbase + ty) * 100 + c]) = z0;
                *(float4*)(&z[(size_t)(rowbase + ty + 16) * 100 + c]) = z1;
            }
        }
    }
}

// ---------------- fused expert chain + loss ---------------------------------
__global__ __launch_bounds__(256) void expert_kernel(
    const float* __restrict__ z, const int* __restrict__ counts,
    const int* __restrict__ idxlist, const float* __restrict__ Wts,
    const float* __restrict__ eb1, const float* __restrict__ eb2,
    const float* __restrict__ eb3, const float* __restrict__ eb4,
    const float* __restrict__ x, const float* __restrict__ xn,
    float* __restrict__ out) {
    int e = blockIdx.y;
    int cnt = counts[e];
    int start = blockIdx.x * 32;
    if (start >= cnt) return;
    int nrows = min(32, cnt - start);

    __shared__ float bufA[32 * 252];   // z gather (ld 100), L2 out (ld 252)
    __shared__ float bufB[32 * 300];   // L1 out (ld 152), L3 out (ld 300)
    __shared__ int s_idx[32];
    __shared__ float s_part[4];

    int tid = threadIdx.x;
    int tx = tid & 15, ty = tid >> 4;

    if (tid < 32)
        s_idx[tid] = (tid < nrows) ? idxlist[e * BATCH + start + tid] : -1;
    __syncthreads();
    for (int i = tid; i < 32 * 100; i += 256) {
        int r = i / 100;
        int k = i - r * 100;
        int b = s_idx[r];
        bufA[i] = (b >= 0) ? z[(size_t)b * 100 + k] : 0.0f;
    }
    __syncthreads();

    const float* W1p = Wts + OFF_EW1P + (size_t)e * 19200;
    const float* W2p = Wts + OFF_EW2P + (size_t)e * 38912;
    const float* W3p = Wts + OFF_EW3P + (size_t)e * 80640;
    const float* W4p = Wts + OFF_EW4P + (size_t)e * 115200;

    mlp_layer<0, 100, 150, 192, 152>(W1p, eb1 + e * 150, bufA, bufB, tx, ty);
    __syncthreads();
    mlp_layer<0, 152, 250, 256, 252>(W2p, eb2 + e * 250, bufB, bufA, tx, ty);
    __syncthreads();
    mlp_layer<0, 252, 300, 320, 300>(W3p, eb3 + e * 300, bufA, bufB, tx, ty);
    __syncthreads();

    // L4 (300 -> 362, no act) fused with loss
    const float WC0 = 1.0f / 65536.0f;
    const float WCR = 1.0f / (361.0f * 65536.0f);
    const float* bias4 = eb4 + (size_t)e * 362;
    const float* a0 = bufB + ty * 300;
    const float* a1 = bufB + (ty + 16) * 300;
    int b0 = s_idx[ty];
    int b1i = s_idx[ty + 16];
    float lacc = 0.0f;
    for (int ct = 0; ct < 6; ++ct) {
        int c = ct * 64 + tx * 4;
        float acc0[4] = {0.f, 0.f, 0.f, 0.f};
        float acc1[4] = {0.f, 0.f, 0.f, 0.f};
        const float* w = W4p + c;
#pragma unroll 2
        for (int k = 0; k < 300; k += 4) {
            float4 va0 = *(const float4*)(a0 + k);
            float4 va1 = *(const float4*)(a1 + k);
            float4 w0 = *(const float4*)(w + (size_t)(k + 0) * 384);
            float4 w1 = *(const float4*)(w + (size_t)(k + 1) * 384);
            float4 w2 = *(const float4*)(w + (size_t)(k + 2) * 384);
            float4 w3 = *(const float4*)(w + (size_t)(k + 3) * 384);
            fma4(acc0, va0.x, w0); fma4(acc0, va0.y, w1);
            fma4(acc0, va0.z, w2); fma4(acc0, va0.w, w3);
            fma4(acc1, va1.x, w0); fma4(acc1, va1.y, w1);
            fma4(acc1, va1.z, w2); fma4(acc1, va1.w, w3);
        }
        if (c < 362) {
            float pv0[4], pv1[4];
#pragma unroll
            for (int j = 0; j < 4; ++j) {
                float bv = (c + j < 362) ? bias4[c + j] : 0.f;
                pv0[j] = acc0[j] + bv;
                pv1[j] = acc1[j] + bv;
            }
            int lim = min(4, 362 - c);
            if (b0 >= 0) {
                const float* xb = x + (size_t)b0 * 362;
                const float* nb = xn + (size_t)b0 * 362;
                if (lim == 4) {
                    float2 xa = *(const float2*)(xb + c), xc = *(const float2*)(xb + c + 2);
                    float2 na = *(const float2*)(nb + c), nc = *(const float2*)(nb + c + 2);
                    float dd[4] = {na.x - xa.x, na.y - xa.y, nc.x - xc.x, nc.y - xc.y};
#pragma unroll
                    for (int j = 0; j < 4; ++j) {
                        float err = pv0[j] - dd[j];
                        lacc += ((c + j == 0) ? WC0 : WCR) * err * err;
                    }
                } else {
                    for (int j = 0; j < lim; ++j) {
                        float err = pv0[j] - (nb[c + j] - xb[c + j]);
                        lacc += WCR * err * err;   // c>=360, never col 0
                    }
                }
            }
            if (b1i >= 0) {
                const float* xb = x + (size_t)b1i * 362;
                const float* nb = xn + (size_t)b1i * 362;
                if (lim == 4) {
                    float2 xa = *(const float2*)(xb + c), xc = *(const float2*)(xb + c + 2);
                    float2 na = *(const float2*)(nb + c), nc = *(const float2*)(nb + c + 2);
                    float dd[4] = {na.x - xa.x, na.y - xa.y, nc.x - xc.x, nc.y - xc.y};
#pragma unroll
                    for (int j = 0; j < 4; ++j) {
                        float err = pv1[j] - dd[j];
                        lacc += ((c + j == 0) ? WC0 : WCR) * err * err;
                    }
                } else {
                    for (int j = 0; j < lim; ++j) {
                        float err = pv1[j] - (nb[c + j] - xb[c + j]);
                        lacc += WCR * err * err;
                    }
                }
            }
        }
    }
    // block reduction -> atomicAdd
    int lane = tid & 63;
    int wid = tid >> 6;
    for (int off = 32; off; off >>= 1)
        lacc += __shfl_down(lacc, off, 64);
    if (lane == 0) s_part[wid] = lacc;
    __syncthreads();
    if (tid == 0) {
        float t = s_part[0] + s_part[1] + s_part[2] + s_part[3];
        atomicAdd(out, t);
    }
}

extern "C" void kernel_launch(void* const* d_in, const int* in_sizes, int n_in,
                              void* d_out, int out_size, void* d_ws, size_t ws_size,
                              hipStream_t stream) {
    const float* x   = (const float*)d_in[0];
    const float* xn  = (const float*)d_in[1];
    const int*   a   = (const int*)d_in[2];
    const float* W1  = (const float*)d_in[3];
    const float* b1  = (const float*)d_in[4];
    const float* W2  = (const float*)d_in[5];
    const float* b2  = (const float*)d_in[6];
    const float* W3  = (const float*)d_in[7];
    const float* b3  = (const float*)d_in[8];
    const float* eW1 = (const float*)d_in[9];
    const float* eb1 = (const float*)d_in[10];
    const float* eW2 = (const float*)d_in[11];
    const float* eb2 = (const float*)d_in[12];
    const float* eW3 = (const float*)d_in[13];
    const float* eb3 = (const float*)d_in[14];
    const float* eW4 = (const float*)d_in[15];
    const float* eb4 = (const float*)d_in[16];

    char* ws = (char*)d_ws;
    int* counts  = (int*)ws;
    int* idxlist = (int*)(ws + WS_IDX_OFF);
    float* z     = (float*)(ws + WS_Z_OFF);
    float* Wts   = (float*)(ws + WS_WT_OFF);

    hipMemsetAsync(counts, 0, 256, stream);
    hipMemsetAsync(d_out, 0, sizeof(float), stream);

    repack_kernel<<<dim3(64, 15), 256, 0, stream>>>(W1, W2, W3, eW1, eW2, eW3, eW4, Wts);
    bucket_kernel<<<BATCH / 256, 256, 0, stream>>>(a, counts, idxlist);
    encoder_kernel<<<BATCH / 32, 256, 0, stream>>>(x, Wts, b1, b2, b3, z);
    expert_kernel<<<dim3(BATCH / 32, 3), 256, 0, stream>>>(
        z, counts, idxlist, Wts, eb1, eb2, eb3, eb4, x, xn, (float*)d_out);
}

// Round 3
// 886.910 us; speedup vs baseline: 6.3410x; 3.3886x over previous
//
#include <hip/hip_runtime.h>
#include <math.h>

// Problem constants
#define BATCH 65536
#define XD 362
#define ZD 100

// ws layout (bytes):
//   [0,256)                : counts[3] (int), zeroed each launch
//   [256, 786688)          : idxlist[3][65536] (int)
//   [786688, +13107200)    : z [B][100] bf16
//   [13893888, +2007040)   : repacked bf16 weights in MFMA B-fragment order
#define WS_IDX_OFF 256
#define WS_Z_OFF   786688
#define WS_WT_OFF  13893888

// Weight offsets in bf16 elements. Fragment order: for each matrix,
// index = ((ct*NKT + kt)*64 + lane)*8 + j, where the fragment element is
// B[k = kt*32 + (lane>>4)*8 + j][n = ct*16 + (lane&15)], zero-padded to Kp,Np.
#define OFF_W1 0        // Kp=384 Np=256
#define OFF_W2 98304    // Kp=256 Np=256
#define OFF_W3 163840   // Kp=224 Np=128
#define OFF_E1 192512   // 3 x Kp=128 Np=192, stride 24576
#define OFF_E2 266240   // 3 x Kp=160 Np=256, stride 40960
#define OFF_E3 389120   // 3 x Kp=256 Np=320, stride 81920
#define OFF_E4 634880   // 3 x Kp=320 Np=384, stride 122880

typedef short short8 __attribute__((ext_vector_type(8)));
typedef float f32x4 __attribute__((ext_vector_type(4)));

__device__ __forceinline__ unsigned short f2bf(float f) {
    union { float f; unsigned u; } v; v.f = f;
    unsigned u = v.u + 0x7fffu + ((v.u >> 16) & 1u);  // RNE
    return (unsigned short)(u >> 16);
}

// ---------------- repack: W[K][N] fp32 -> bf16 MFMA B-fragment order --------
__global__ __launch_bounds__(256) void repack_kernel(
    const float* __restrict__ W1, const float* __restrict__ W2,
    const float* __restrict__ W3, const float* __restrict__ eW1,
    const float* __restrict__ eW2, const float* __restrict__ eW3,
    const float* __restrict__ eW4, unsigned short* __restrict__ dst) {
    int m = blockIdx.y;
    const float* src; int K, N, Kp, Np; size_t off;
    if (m == 0)      { src = W1; K = 362; N = 256; Kp = 384; Np = 256; off = OFF_W1; }
    else if (m == 1) { src = W2; K = 256; N = 200; Kp = 256; Np = 256; off = OFF_W2; }
    else if (m == 2) { src = W3; K = 200; N = 100; Kp = 224; Np = 128; off = OFF_W3; }
    else if (m <= 5) { int e = m - 3;  src = eW1 + e * 15000;  K = 100; N = 150; Kp = 128; Np = 192; off = OFF_E1 + (size_t)e * 24576; }
    else if (m <= 8) { int e = m - 6;  src = eW2 + e * 37500;  K = 150; N = 250; Kp = 160; Np = 256; off = OFF_E2 + (size_t)e * 40960; }
    else if (m <= 11){ int e = m - 9;  src = eW3 + e * 75000;  K = 250; N = 300; Kp = 256; Np = 320; off = OFF_E3 + (size_t)e * 81920; }
    else             { int e = m - 12; src = eW4 + e * 108600; K = 300; N = 362; Kp = 320; Np = 384; off = OFF_E4 + (size_t)e * 122880; }
    int nkt = Kp / 32;
    int total = Kp * Np;
    for (int i = blockIdx.x * 256 + threadIdx.x; i < total; i += gridDim.x * 256) {
        int j = i & 7, lane = (i >> 3) & 63, t = i >> 9;
        int kt = t % nkt, ct = t / nkt;
        int k = kt * 32 + (lane >> 4) * 8 + j;
        int n = ct * 16 + (lane & 15);
        float v = (k < K && n < N) ? src[(size_t)k * N + n] : 0.0f;
        dst[off + i] = f2bf(v);
    }
}

// ---------------- bucket rows by expert -------------------------------------
__global__ __launch_bounds__(256) void bucket_kernel(const int* __restrict__ a,
                                                     int* __restrict__ counts,
                                                     int* __restrict__ idxlist) {
    int b = blockIdx.x * 256 + threadIdx.x;
    if (b >= BATCH) return;
    int e = a[b];
    int pos = atomicAdd(&counts[e], 1);
    idxlist[e * BATCH + pos] = b;
}

// Generic MFMA layer over a 32-row LDS tile.
// in: bf16 LDS [32][LDI] (zero-padded to KP). out: bf16 LDS [32][LDO],
// relu(acc+bias), cols n<NSTORE written, zeros for n>=NREAL.
// Wave wv owns col-tiles {wv, wv+4, ...}. A-frag: [m=lane&15][k=quad*8+j];
// B-frag from pre-swizzled global; C/D: row=quad*4+reg, col=lane&15.
template <int KP, int NP, int LDI, int LDO, int NREAL, int NSTORE>
__device__ __forceinline__ void mfma_layer(
    const unsigned short* __restrict__ Wf, const float* __restrict__ bias,
    const unsigned short* __restrict__ inL, unsigned short* __restrict__ outL,
    int wv, int lane) {
    constexpr int NKT = KP / 32, NCT = NP / 16, CPW = NCT / 4;
    const int quad = lane >> 4, l15 = lane & 15;
    f32x4 acc[CPW][2];
#pragma unroll
    for (int i = 0; i < CPW; ++i) {
        acc[i][0] = (f32x4){0.f, 0.f, 0.f, 0.f};
        acc[i][1] = (f32x4){0.f, 0.f, 0.f, 0.f};
    }
    const unsigned short* a0p = inL + l15 * LDI + quad * 8;
    const unsigned short* a1p = a0p + 16 * LDI;
#pragma unroll 2
    for (int kt = 0; kt < NKT; ++kt) {
        short8 a0 = *(const short8*)(a0p + kt * 32);
        short8 a1 = *(const short8*)(a1p + kt * 32);
        short8 bf[CPW];
#pragma unroll
        for (int i = 0; i < CPW; ++i)
            bf[i] = *(const short8*)(Wf + ((size_t)((wv + 4 * i) * NKT + kt) * 64 + lane) * 8);
#pragma unroll
        for (int i = 0; i < CPW; ++i) {
            acc[i][0] = __builtin_amdgcn_mfma_f32_16x16x32_bf16(a0, bf[i], acc[i][0], 0, 0, 0);
            acc[i][1] = __builtin_amdgcn_mfma_f32_16x16x32_bf16(a1, bf[i], acc[i][1], 0, 0, 0);
        }
    }
#pragma unroll
    for (int i = 0; i < CPW; ++i) {
        int n = (wv + 4 * i) * 16 + l15;
        if (n < NSTORE) {
            float bv = (n < NREAL) ? bias[n] : 0.f;
            unsigned short ov;
#pragma unroll
            for (int rt = 0; rt < 2; ++rt)
#pragma unroll
                for (int r = 0; r < 4; ++r) {
                    int row = rt * 16 + quad * 4 + r;
                    float v = fmaxf(acc[i][rt][r] + bv, 0.f);
                    ov = (n < NREAL) ? f2bf(v) : (unsigned short)0;
                    outL[row * LDO + n] = ov;
                }
        }
    }
}

// ---------------- fused encoder: x -> z (bf16) ------------------------------
__global__ __launch_bounds__(256) void encoder_kernel(
    const float* __restrict__ x, const unsigned short* __restrict__ Wts,
    const float* __restrict__ b1, const float* __restrict__ b2,
    const float* __restrict__ b3, unsigned short* __restrict__ z) {
    __shared__ unsigned short bufA[32 * 392];  // x (ld392,Kp384) then h2 (ld264)
    __shared__ unsigned short bufB[32 * 264];  // h1 (ld264,Kp256)
    int tid = threadIdx.x;
    int wv = tid >> 6, lane = tid & 63;
    int rowbase = blockIdx.x * 32;
    // stage x -> bf16 pairs, ld 392 (196 dwords), zero-pad k>=362
    unsigned* dA = (unsigned*)bufA;
    for (int i = tid; i < 32 * 196; i += 256) {
        int r = i / 196, c = i - r * 196;
        unsigned pk = 0u;
        if (c < 181) {
            float2 v = *(const float2*)(x + (size_t)(rowbase + r) * 362 + 2 * c);
            pk = (unsigned)f2bf(v.x) | ((unsigned)f2bf(v.y) << 16);
        }
        dA[r * 196 + c] = pk;
    }
    __syncthreads();
    mfma_layer<384, 256, 392, 264, 256, 256>(Wts + OFF_W1, b1, bufA, bufB, wv, lane);
    __syncthreads();
    mfma_layer<256, 256, 264, 264, 200, 256>(Wts + OFF_W2, b2, bufB, bufA, wv, lane);
    __syncthreads();
    // L3: Kp=224, Np=128 (real 100), sigmoid, write z bf16 [B][100]
    {
        constexpr int NKT = 7, CPW = 2;
        const unsigned short* Wf = Wts + OFF_W3;
        const int quad = lane >> 4, l15 = lane & 15;
        f32x4 acc[CPW][2];
#pragma unroll
        for (int i = 0; i < CPW; ++i) {
            acc[i][0] = (f32x4){0.f, 0.f, 0.f, 0.f};
            acc[i][1] = (f32x4){0.f, 0.f, 0.f, 0.f};
        }
        const unsigned short* a0p = bufA + l15 * 264 + quad * 8;
        const unsigned short* a1p = a0p + 16 * 264;
#pragma unroll 2
        for (int kt = 0; kt < NKT; ++kt) {
            short8 a0 = *(const short8*)(a0p + kt * 32);
            short8 a1 = *(const short8*)(a1p + kt * 32);
            short8 bf[CPW];
#pragma unroll
            for (int i = 0; i < CPW; ++i)
                bf[i] = *(const short8*)(Wf + ((size_t)((wv + 4 * i) * NKT + kt) * 64 + lane) * 8);
#pragma unroll
            for (int i = 0; i < CPW; ++i) {
                acc[i][0] = __builtin_amdgcn_mfma_f32_16x16x32_bf16(a0, bf[i], acc[i][0], 0, 0, 0);
                acc[i][1] = __builtin_amdgcn_mfma_f32_16x16x32_bf16(a1, bf[i], acc[i][1], 0, 0, 0);
            }
        }
#pragma unroll
        for (int i = 0; i < CPW; ++i) {
            int n = (wv + 4 * i) * 16 + l15;
            if (n < 100) {
                float bv = b3[n];
#pragma unroll
                for (int rt = 0; rt < 2; ++rt)
#pragma unroll
                    for (int r = 0; r < 4; ++r) {
                        int row = rowbase + rt * 16 + quad * 4 + r;
                        float v = acc[i][rt][r] + bv;
                        float s = 1.0f / (1.0f + expf(-v));
                        z[(size_t)row * 100 + n] = f2bf(s);
                    }
            }
        }
    }
}

// ---------------- fused expert chain + loss ---------------------------------
__global__ __launch_bounds__(256) void expert_kernel(
    const unsigned short* __restrict__ z, const int* __restrict__ counts,
    const int* __restrict__ idxlist, const unsigned short* __restrict__ Wts,
    const float* __restrict__ eb1, const float* __restrict__ eb2,
    const float* __restrict__ eb3, const float* __restrict__ eb4,
    const float* __restrict__ x, const float* __restrict__ xn,
    float* __restrict__ out) {
    int e = blockIdx.y;
    int cnt = counts[e];
    int start = blockIdx.x * 32;
    if (start >= cnt) return;
    int nrows = min(32, cnt - start);

    __shared__ unsigned short bufA[32 * 264];  // z (ld136) then h2 (ld264)
    __shared__ unsigned short bufB[32 * 328];  // h1 (ld168) then h3 (ld328)
    __shared__ int s_idx[32];
    __shared__ float s_part[4];

    int tid = threadIdx.x;
    int wv = tid >> 6, lane = tid & 63;

    if (tid < 32)
        s_idx[tid] = (tid < nrows) ? idxlist[e * BATCH + start + tid] : -1;
    __syncthreads();
    // gather z rows (bf16 pairs as dwords), ld 136 (68 dwords), pad k>=100
    {
        unsigned* dA = (unsigned*)bufA;
        const unsigned* zd = (const unsigned*)z;
        for (int i = tid; i < 32 * 68; i += 256) {
            int r = i / 68, c = i - r * 68;
            int b = s_idx[r];
            dA[r * 68 + c] = (b >= 0 && c < 50) ? zd[(size_t)b * 50 + c] : 0u;
        }
    }
    __syncthreads();
    mfma_layer<128, 192, 136, 168, 150, 160>(Wts + OFF_E1 + (size_t)e * 24576,
                                             eb1 + e * 150, bufA, bufB, wv, lane);
    __syncthreads();
    mfma_layer<160, 256, 168, 264, 250, 256>(Wts + OFF_E2 + (size_t)e * 40960,
                                             eb2 + e * 250, bufB, bufA, wv, lane);
    __syncthreads();
    mfma_layer<256, 320, 264, 328, 300, 320>(Wts + OFF_E3 + (size_t)e * 81920,
                                             eb3 + e * 300, bufA, bufB, wv, lane);
    __syncthreads();

    // L4: Kp=320, Np=384 (real 362), fused with loss from accumulators
    float lacc = 0.0f;
    {
        constexpr int NKT = 10, CPW = 6;
        const unsigned short* Wf = Wts + OFF_E4 + (size_t)e * 122880;
        const float* bias4 = eb4 + (size_t)e * 362;
        const int quad = lane >> 4, l15 = lane & 15;
        f32x4 acc[CPW][2];
#pragma unroll
        for (int i = 0; i < CPW; ++i) {
            acc[i][0] = (f32x4){0.f, 0.f, 0.f, 0.f};
            acc[i][1] = (f32x4){0.f, 0.f, 0.f, 0.f};
        }
        const unsigned short* a0p = bufB + l15 * 328 + quad * 8;
        const unsigned short* a1p = a0p + 16 * 328;
#pragma unroll 2
        for (int kt = 0; kt < NKT; ++kt) {
            short8 a0 = *(const short8*)(a0p + kt * 32);
            short8 a1 = *(const short8*)(a1p + kt * 32);
            short8 bf[CPW];
#pragma unroll
            for (int i = 0; i < CPW; ++i)
                bf[i] = *(const short8*)(Wf + ((size_t)((wv + 4 * i) * NKT + kt) * 64 + lane) * 8);
#pragma unroll
            for (int i = 0; i < CPW; ++i) {
                acc[i][0] = __builtin_amdgcn_mfma_f32_16x16x32_bf16(a0, bf[i], acc[i][0], 0, 0, 0);
                acc[i][1] = __builtin_amdgcn_mfma_f32_16x16x32_bf16(a1, bf[i], acc[i][1], 0, 0, 0);
            }
        }
        const float WC0 = 1.0f / 65536.0f;
        const float WCR = 1.0f / (361.0f * 65536.0f);
#pragma unroll
        for (int i = 0; i < CPW; ++i) {
            int n = (wv + 4 * i) * 16 + l15;
            if (n < 362) {
                float bv = bias4[n];
                float wgt = (n == 0) ? WC0 : WCR;
#pragma unroll
                for (int rt = 0; rt < 2; ++rt) {
                    int row = rt * 16 + quad * 4;
#pragma unroll
                    for (int r = 0; r < 4; ++r) {
                        int b = s_idx[row + r];
                        if (b >= 0) {
                            float pred = acc[i][rt][r] + bv;
                            float delta = xn[(size_t)b * 362 + n] - x[(size_t)b * 362 + n];
                            float err = pred - delta;
                            lacc += wgt * err * err;
                        }
                    }
                }
            }
        }
    }
    // block reduction -> atomicAdd
    for (int off = 32; off; off >>= 1)
        lacc += __shfl_down(lacc, off, 64);
    if ((tid & 63) == 0) s_part[wv] = lacc;
    __syncthreads();
    if (tid == 0)
        atomicAdd(out, s_part[0] + s_part[1] + s_part[2] + s_part[3]);
}

extern "C" void kernel_launch(void* const* d_in, const int* in_sizes, int n_in,
                              void* d_out, int out_size, void* d_ws, size_t ws_size,
                              hipStream_t stream) {
    const float* x   = (const float*)d_in[0];
    const float* xn  = (const float*)d_in[1];
    const int*   a   = (const int*)d_in[2];
    const float* W1  = (const float*)d_in[3];
    const float* b1  = (const float*)d_in[4];
    const float* W2  = (const float*)d_in[5];
    const float* b2  = (const float*)d_in[6];
    const float* W3  = (const float*)d_in[7];
    const float* b3  = (const float*)d_in[8];
    const float* eW1 = (const float*)d_in[9];
    const float* eb1 = (const float*)d_in[10];
    const float* eW2 = (const float*)d_in[11];
    const float* eb2 = (const float*)d_in[12];
    const float* eW3 = (const float*)d_in[13];
    const float* eb3 = (const float*)d_in[14];
    const float* eW4 = (const float*)d_in[15];
    const float* eb4 = (const float*)d_in[16];

    char* ws = (char*)d_ws;
    int* counts           = (int*)ws;
    int* idxlist          = (int*)(ws + WS_IDX_OFF);
    unsigned short* z     = (unsigned short*)(ws + WS_Z_OFF);
    unsigned short* Wts   = (unsigned short*)(ws + WS_WT_OFF);

    hipMemsetAsync(counts, 0, 256, stream);
    hipMemsetAsync(d_out, 0, sizeof(float), stream);

    repack_kernel<<<dim3(32, 15), 256, 0, stream>>>(W1, W2, W3, eW1, eW2, eW3, eW4, Wts);
    bucket_kernel<<<BATCH / 256, 256, 0, stream>>>(a, counts, idxlist);
    encoder_kernel<<<BATCH / 32, 256, 0, stream>>>(x, Wts, b1, b2, b3, z);
    expert_kernel<<<dim3(BATCH / 32, 3), 256, 0, stream>>>(
        z, counts, idxlist, Wts, eb1, eb2, eb3, eb4, x, xn, (float*)d_out);
}

// Round 4
// 505.741 us; speedup vs baseline: 11.1200x; 1.7537x over previous
//
#include <hip/hip_runtime.h>
#include <math.h>

// Problem constants
#define BATCH 65536
#define XD 362
#define ZD 100

// ws layout (bytes):
//   [0,256)                : counts[3] (int), zeroed each launch
//   [256, 786688)          : idxlist[3][65536] (int)
//   [786688, +13107200)    : z [B][100] bf16
//   [13893888, +2007040)   : repacked bf16 weights in MFMA B-fragment order
#define WS_IDX_OFF 256
#define WS_Z_OFF   786688
#define WS_WT_OFF  13893888

// Weight offsets in bf16 elements. Fragment order: for each matrix,
// index = ((ct*NKT + kt)*64 + lane)*8 + j, where the fragment element is
// B[k = kt*32 + (lane>>4)*8 + j][n = ct*16 + (lane&15)], zero-padded to Kp,Np.
#define OFF_W1 0        // Kp=384 Np=256
#define OFF_W2 98304    // Kp=256 Np=256
#define OFF_W3 163840   // Kp=224 Np=128
#define OFF_E1 192512   // 3 x Kp=128 Np=192, stride 24576
#define OFF_E2 266240   // 3 x Kp=160 Np=256, stride 40960
#define OFF_E3 389120   // 3 x Kp=256 Np=320, stride 81920
#define OFF_E4 634880   // 3 x Kp=320 Np=384, stride 122880

typedef short short8 __attribute__((ext_vector_type(8)));
typedef float f32x4 __attribute__((ext_vector_type(4)));

__device__ __forceinline__ unsigned short f2bf(float f) {
    union { float f; unsigned u; } v; v.f = f;
    unsigned u = v.u + 0x7fffu + ((v.u >> 16) & 1u);  // RNE
    return (unsigned short)(u >> 16);
}

// ---------------- repack: W[K][N] fp32 -> bf16 MFMA B-fragment order --------
__global__ __launch_bounds__(256) void repack_kernel(
    const float* __restrict__ W1, const float* __restrict__ W2,
    const float* __restrict__ W3, const float* __restrict__ eW1,
    const float* __restrict__ eW2, const float* __restrict__ eW3,
    const float* __restrict__ eW4, unsigned short* __restrict__ dst) {
    int m = blockIdx.y;
    const float* src; int K, N, Kp, Np; size_t off;
    if (m == 0)      { src = W1; K = 362; N = 256; Kp = 384; Np = 256; off = OFF_W1; }
    else if (m == 1) { src = W2; K = 256; N = 200; Kp = 256; Np = 256; off = OFF_W2; }
    else if (m == 2) { src = W3; K = 200; N = 100; Kp = 224; Np = 128; off = OFF_W3; }
    else if (m <= 5) { int e = m - 3;  src = eW1 + e * 15000;  K = 100; N = 150; Kp = 128; Np = 192; off = OFF_E1 + (size_t)e * 24576; }
    else if (m <= 8) { int e = m - 6;  src = eW2 + e * 37500;  K = 150; N = 250; Kp = 160; Np = 256; off = OFF_E2 + (size_t)e * 40960; }
    else if (m <= 11){ int e = m - 9;  src = eW3 + e * 75000;  K = 250; N = 300; Kp = 256; Np = 320; off = OFF_E3 + (size_t)e * 81920; }
    else             { int e = m - 12; src = eW4 + e * 108600; K = 300; N = 362; Kp = 320; Np = 384; off = OFF_E4 + (size_t)e * 122880; }
    int nkt = Kp / 32;
    int total = Kp * Np;
    for (int i = blockIdx.x * 256 + threadIdx.x; i < total; i += gridDim.x * 256) {
        int j = i & 7, lane = (i >> 3) & 63, t = i >> 9;
        int kt = t % nkt, ct = t / nkt;
        int k = kt * 32 + (lane >> 4) * 8 + j;
        int n = ct * 16 + (lane & 15);
        float v = (k < K && n < N) ? src[(size_t)k * N + n] : 0.0f;
        dst[off + i] = f2bf(v);
    }
}

// ---------------- bucket rows by expert (wave-aggregated atomics) -----------
// Order within a bucket is irrelevant (pure gather list), so each wave does
// ONE atomicAdd per expert (3/wave vs 64 per-thread serialized RMWs).
__global__ __launch_bounds__(256) void bucket_kernel(const int* __restrict__ a,
                                                     int* __restrict__ counts,
                                                     int* __restrict__ idxlist) {
    int b = blockIdx.x * 256 + threadIdx.x;
    int lane = threadIdx.x & 63;
    int e = a[b];
    unsigned long long below = (lane == 63) ? ~0ull >> 1
                                            : ((1ull << (lane + 1)) - 1ull) >> 1;
    int pos = 0;
#pragma unroll
    for (int ee = 0; ee < 3; ++ee) {
        unsigned long long mask = __ballot(e == ee);
        if (e == ee) {
            int leader = __ffsll((long long)mask) - 1;
            int base = 0;
            if (lane == leader)
                base = atomicAdd(&counts[ee], __popcll(mask));
            base = __shfl(base, leader, 64);
            pos = base + __popcll(mask & below);
        }
    }
    idxlist[e * BATCH + pos] = b;
}

// Generic MFMA layer over a 32-row LDS tile.
// in: bf16 LDS [32][LDI] (zero-padded to KP). out: bf16 LDS [32][LDO],
// relu(acc+bias), cols n<NSTORE written, zeros for n>=NREAL.
// Wave wv owns col-tiles {wv, wv+4, ...}. A-frag: [m=lane&15][k=quad*8+j];
// B-frag from pre-swizzled global; C/D: row=quad*4+reg, col=lane&15.
template <int KP, int NP, int LDI, int LDO, int NREAL, int NSTORE>
__device__ __forceinline__ void mfma_layer(
    const unsigned short* __restrict__ Wf, const float* __restrict__ bias,
    const unsigned short* __restrict__ inL, unsigned short* __restrict__ outL,
    int wv, int lane) {
    constexpr int NKT = KP / 32, NCT = NP / 16, CPW = NCT / 4;
    const int quad = lane >> 4, l15 = lane & 15;
    f32x4 acc[CPW][2];
#pragma unroll
    for (int i = 0; i < CPW; ++i) {
        acc[i][0] = (f32x4){0.f, 0.f, 0.f, 0.f};
        acc[i][1] = (f32x4){0.f, 0.f, 0.f, 0.f};
    }
    const unsigned short* a0p = inL + l15 * LDI + quad * 8;
    const unsigned short* a1p = a0p + 16 * LDI;
#pragma unroll 2
    for (int kt = 0; kt < NKT; ++kt) {
        short8 a0 = *(const short8*)(a0p + kt * 32);
        short8 a1 = *(const short8*)(a1p + kt * 32);
        short8 bf[CPW];
#pragma unroll
        for (int i = 0; i < CPW; ++i)
            bf[i] = *(const short8*)(Wf + ((size_t)((wv + 4 * i) * NKT + kt) * 64 + lane) * 8);
#pragma unroll
        for (int i = 0; i < CPW; ++i) {
            acc[i][0] = __builtin_amdgcn_mfma_f32_16x16x32_bf16(a0, bf[i], acc[i][0], 0, 0, 0);
            acc[i][1] = __builtin_amdgcn_mfma_f32_16x16x32_bf16(a1, bf[i], acc[i][1], 0, 0, 0);
        }
    }
#pragma unroll
    for (int i = 0; i < CPW; ++i) {
        int n = (wv + 4 * i) * 16 + l15;
        if (n < NSTORE) {
            float bv = (n < NREAL) ? bias[n] : 0.f;
            unsigned short ov;
#pragma unroll
            for (int rt = 0; rt < 2; ++rt)
#pragma unroll
                for (int r = 0; r < 4; ++r) {
                    int row = rt * 16 + quad * 4 + r;
                    float v = fmaxf(acc[i][rt][r] + bv, 0.f);
                    ov = (n < NREAL) ? f2bf(v) : (unsigned short)0;
                    outL[row * LDO + n] = ov;
                }
        }
    }
}

// ---------------- fused encoder: x -> z (bf16) ------------------------------
__global__ __launch_bounds__(256) void encoder_kernel(
    const float* __restrict__ x, const unsigned short* __restrict__ Wts,
    const float* __restrict__ b1, const float* __restrict__ b2,
    const float* __restrict__ b3, unsigned short* __restrict__ z) {
    __shared__ unsigned short bufA[32 * 392];  // x (ld392,Kp384) then h2 (ld264)
    __shared__ unsigned short bufB[32 * 264];  // h1 (ld264,Kp256)
    int tid = threadIdx.x;
    int wv = tid >> 6, lane = tid & 63;
    int rowbase = blockIdx.x * 32;
    // stage x -> bf16 pairs, ld 392 (196 dwords), zero-pad k>=362
    unsigned* dA = (unsigned*)bufA;
    for (int i = tid; i < 32 * 196; i += 256) {
        int r = i / 196, c = i - r * 196;
        unsigned pk = 0u;
        if (c < 181) {
            float2 v = *(const float2*)(x + (size_t)(rowbase + r) * 362 + 2 * c);
            pk = (unsigned)f2bf(v.x) | ((unsigned)f2bf(v.y) << 16);
        }
        dA[r * 196 + c] = pk;
    }
    __syncthreads();
    mfma_layer<384, 256, 392, 264, 256, 256>(Wts + OFF_W1, b1, bufA, bufB, wv, lane);
    __syncthreads();
    mfma_layer<256, 256, 264, 264, 200, 256>(Wts + OFF_W2, b2, bufB, bufA, wv, lane);
    __syncthreads();
    // L3: Kp=224, Np=128 (real 100), sigmoid, write z bf16 [B][100]
    {
        constexpr int NKT = 7, CPW = 2;
        const unsigned short* Wf = Wts + OFF_W3;
        const int quad = lane >> 4, l15 = lane & 15;
        f32x4 acc[CPW][2];
#pragma unroll
        for (int i = 0; i < CPW; ++i) {
            acc[i][0] = (f32x4){0.f, 0.f, 0.f, 0.f};
            acc[i][1] = (f32x4){0.f, 0.f, 0.f, 0.f};
        }
        const unsigned short* a0p = bufA + l15 * 264 + quad * 8;
        const unsigned short* a1p = a0p + 16 * 264;
#pragma unroll 2
        for (int kt = 0; kt < NKT; ++kt) {
            short8 a0 = *(const short8*)(a0p + kt * 32);
            short8 a1 = *(const short8*)(a1p + kt * 32);
            short8 bf[CPW];
#pragma unroll
            for (int i = 0; i < CPW; ++i)
                bf[i] = *(const short8*)(Wf + ((size_t)((wv + 4 * i) * NKT + kt) * 64 + lane) * 8);
#pragma unroll
            for (int i = 0; i < CPW; ++i) {
                acc[i][0] = __builtin_amdgcn_mfma_f32_16x16x32_bf16(a0, bf[i], acc[i][0], 0, 0, 0);
                acc[i][1] = __builtin_amdgcn_mfma_f32_16x16x32_bf16(a1, bf[i], acc[i][1], 0, 0, 0);
            }
        }
#pragma unroll
        for (int i = 0; i < CPW; ++i) {
            int n = (wv + 4 * i) * 16 + l15;
            if (n < 100) {
                float bv = b3[n];
#pragma unroll
                for (int rt = 0; rt < 2; ++rt)
#pragma unroll
                    for (int r = 0; r < 4; ++r) {
                        int row = rowbase + rt * 16 + quad * 4 + r;
                        float v = acc[i][rt][r] + bv;
                        float s = 1.0f / (1.0f + expf(-v));
                        z[(size_t)row * 100 + n] = f2bf(s);
                    }
            }
        }
    }
}

// ---------------- fused expert chain + loss ---------------------------------
__global__ __launch_bounds__(256) void expert_kernel(
    const unsigned short* __restrict__ z, const int* __restrict__ counts,
    const int* __restrict__ idxlist, const unsigned short* __restrict__ Wts,
    const float* __restrict__ eb1, const float* __restrict__ eb2,
    const float* __restrict__ eb3, const float* __restrict__ eb4,
    const float* __restrict__ x, const float* __restrict__ xn,
    float* __restrict__ out) {
    int e = blockIdx.y;
    int cnt = counts[e];
    int start = blockIdx.x * 32;
    if (start >= cnt) return;
    int nrows = min(32, cnt - start);

    __shared__ unsigned short bufA[32 * 264];  // z (ld136) then h2 (ld264)
    __shared__ unsigned short bufB[32 * 328];  // h1 (ld168) then h3 (ld328)
    __shared__ int s_idx[32];
    __shared__ float s_part[4];

    int tid = threadIdx.x;
    int wv = tid >> 6, lane = tid & 63;

    if (tid < 32)
        s_idx[tid] = (tid < nrows) ? idxlist[e * BATCH + start + tid] : -1;
    __syncthreads();
    // gather z rows (bf16 pairs as dwords), ld 136 (68 dwords), pad k>=100
    {
        unsigned* dA = (unsigned*)bufA;
        const unsigned* zd = (const unsigned*)z;
        for (int i = tid; i < 32 * 68; i += 256) {
            int r = i / 68, c = i - r * 68;
            int b = s_idx[r];
            dA[r * 68 + c] = (b >= 0 && c < 50) ? zd[(size_t)b * 50 + c] : 0u;
        }
    }
    __syncthreads();
    mfma_layer<128, 192, 136, 168, 150, 160>(Wts + OFF_E1 + (size_t)e * 24576,
                                             eb1 + e * 150, bufA, bufB, wv, lane);
    __syncthreads();
    mfma_layer<160, 256, 168, 264, 250, 256>(Wts + OFF_E2 + (size_t)e * 40960,
                                             eb2 + e * 250, bufB, bufA, wv, lane);
    __syncthreads();
    mfma_layer<256, 320, 264, 328, 300, 320>(Wts + OFF_E3 + (size_t)e * 81920,
                                             eb3 + e * 300, bufA, bufB, wv, lane);
    __syncthreads();

    // L4: Kp=320, Np=384 (real 362), fused with loss from accumulators
    float lacc = 0.0f;
    {
        constexpr int NKT = 10, CPW = 6;
        const unsigned short* Wf = Wts + OFF_E4 + (size_t)e * 122880;
        const float* bias4 = eb4 + (size_t)e * 362;
        const int quad = lane >> 4, l15 = lane & 15;
        f32x4 acc[CPW][2];
#pragma unroll
        for (int i = 0; i < CPW; ++i) {
            acc[i][0] = (f32x4){0.f, 0.f, 0.f, 0.f};
            acc[i][1] = (f32x4){0.f, 0.f, 0.f, 0.f};
        }
        const unsigned short* a0p = bufB + l15 * 328 + quad * 8;
        const unsigned short* a1p = a0p + 16 * 328;
#pragma unroll 2
        for (int kt = 0; kt < NKT; ++kt) {
            short8 a0 = *(const short8*)(a0p + kt * 32);
            short8 a1 = *(const short8*)(a1p + kt * 32);
            short8 bf[CPW];
#pragma unroll
            for (int i = 0; i < CPW; ++i)
                bf[i] = *(const short8*)(Wf + ((size_t)((wv + 4 * i) * NKT + kt) * 64 + lane) * 8);
#pragma unroll
            for (int i = 0; i < CPW; ++i) {
                acc[i][0] = __builtin_amdgcn_mfma_f32_16x16x32_bf16(a0, bf[i], acc[i][0], 0, 0, 0);
                acc[i][1] = __builtin_amdgcn_mfma_f32_16x16x32_bf16(a1, bf[i], acc[i][1], 0, 0, 0);
            }
        }
        const float WC0 = 1.0f / 65536.0f;
        const float WCR = 1.0f / (361.0f * 65536.0f);
#pragma unroll
        for (int i = 0; i < CPW; ++i) {
            int n = (wv + 4 * i) * 16 + l15;
            if (n < 362) {
                float bv = bias4[n];
                float wgt = (n == 0) ? WC0 : WCR;
#pragma unroll
                for (int rt = 0; rt < 2; ++rt) {
                    int row = rt * 16 + quad * 4;
#pragma unroll
                    for (int r = 0; r < 4; ++r) {
                        int b = s_idx[row + r];
                        if (b >= 0) {
                            float pred = acc[i][rt][r] + bv;
                            float delta = xn[(size_t)b * 362 + n] - x[(size_t)b * 362 + n];
                            float err = pred - delta;
                            lacc += wgt * err * err;
                        }
                    }
                }
            }
        }
    }
    // block reduction -> atomicAdd
    for (int off = 32; off; off >>= 1)
        lacc += __shfl_down(lacc, off, 64);
    if ((tid & 63) == 0) s_part[wv] = lacc;
    __syncthreads();
    if (tid == 0)
        atomicAdd(out, s_part[0] + s_part[1] + s_part[2] + s_part[3]);
}

extern "C" void kernel_launch(void* const* d_in, const int* in_sizes, int n_in,
                              void* d_out, int out_size, void* d_ws, size_t ws_size,
                              hipStream_t stream) {
    const float* x   = (const float*)d_in[0];
    const float* xn  = (const float*)d_in[1];
    const int*   a   = (const int*)d_in[2];
    const float* W1  = (const float*)d_in[3];
    const float* b1  = (const float*)d_in[4];
    const float* W2  = (const float*)d_in[5];
    const float* b2  = (const float*)d_in[6];
    const float* W3  = (const float*)d_in[7];
    const float* b3  = (const float*)d_in[8];
    const float* eW1 = (const float*)d_in[9];
    const float* eb1 = (const float*)d_in[10];
    const float* eW2 = (const float*)d_in[11];
    const float* eb2 = (const float*)d_in[12];
    const float* eW3 = (const float*)d_in[13];
    const float* eb3 = (const float*)d_in[14];
    const float* eW4 = (const float*)d_in[15];
    const float* eb4 = (const float*)d_in[16];

    char* ws = (char*)d_ws;
    int* counts           = (int*)ws;
    int* idxlist          = (int*)(ws + WS_IDX_OFF);
    unsigned short* z     = (unsigned short*)(ws + WS_Z_OFF);
    unsigned short* Wts   = (unsigned short*)(ws + WS_WT_OFF);

    hipMemsetAsync(counts, 0, 256, stream);
    hipMemsetAsync(d_out, 0, sizeof(float), stream);

    repack_kernel<<<dim3(32, 15), 256, 0, stream>>>(W1, W2, W3, eW1, eW2, eW3, eW4, Wts);
    bucket_kernel<<<BATCH / 256, 256, 0, stream>>>(a, counts, idxlist);
    encoder_kernel<<<BATCH / 32, 256, 0, stream>>>(x, Wts, b1, b2, b3, z);
    expert_kernel<<<dim3(BATCH / 32, 3), 256, 0, stream>>>(
        z, counts, idxlist, Wts, eb1, eb2, eb3, eb4, x, xn, (float*)d_out);
}